// Round 3
// baseline (122.925 us; speedup 1.0000x reference)
//
#include <hip/hip_runtime.h>
#include <math.h>

#define N_PL 16
#define NT   17      // N_PL+1
#define OBJ  10
#define M    36
#define SPB  4       // samples per block
#define BLK  64      // one wave per block; 16 lanes per sample

// packed (i<<4)|j pair tables
__constant__ unsigned char c_p55[55] = {
 0x00,0x01,0x02,0x03,0x04,0x05,0x06,0x07,0x08,0x09,
 0x11,0x12,0x13,0x14,0x15,0x16,0x17,0x18,0x19,
 0x22,0x23,0x24,0x25,0x26,0x27,0x28,0x29,
 0x33,0x34,0x35,0x36,0x37,0x38,0x39,
 0x44,0x45,0x46,0x47,0x48,0x49,
 0x55,0x56,0x57,0x58,0x59,
 0x66,0x67,0x68,0x69,
 0x77,0x78,0x79,
 0x88,0x89,
 0x99};
__constant__ unsigned char c_p45[45] = {
 0x01,0x02,0x03,0x04,0x05,0x06,0x07,0x08,0x09,
 0x12,0x13,0x14,0x15,0x16,0x17,0x18,0x19,
 0x23,0x24,0x25,0x26,0x27,0x28,0x29,
 0x34,0x35,0x36,0x37,0x38,0x39,
 0x45,0x46,0x47,0x48,0x49,
 0x56,0x57,0x58,0x59,
 0x67,0x68,0x69,
 0x78,0x79,
 0x89};

// plin: s_tab[0..135] = wn[8][17], s_tab[136..271] = cs[8][17]
__device__ __forceinline__ float plin_tab(const float* s_tab, int t, float x) {
    const float* wn = s_tab + t * NT;
    const float* cs = s_tab + 136 + t * NT;
    float y = 16.0f * x;
    int idx = (int)y;
    float f = y - (float)idx;
    int i0 = idx < N_PL ? idx : N_PL;
    int i1 = (idx + 1) < N_PL ? (idx + 1) : N_PL;
    return __builtin_fmaf(f, wn[i1], cs[i0]);
}

__device__ __forceinline__ unsigned long long mkkey(float v, int m) {
    unsigned int b = __float_as_uint(v);
    unsigned int u = b ^ (0x80000000u | (unsigned int)((int)b >> 31));
    return ((unsigned long long)u << 6) | (unsigned int)(63 - m);
}

__global__ __launch_bounds__(BLK, 6) void counter_kernel(
    const float* __restrict__ boxes,   // [n,4,36]
    const float* __restrict__ attn,    // [n,36]
    const float* __restrict__ ws,      // [8,17]
    float* __restrict__ out,           // [n,11]
    int n)
{
    __shared__ float s_tab[272];
    __shared__ float s_att[OBJ][SPB];
    __shared__ float s_box[5][OBJ][SPB];       // x0,y0,x1,y1,area
    __shared__ float s_dedup[OBJ * OBJ][SPB];
    __shared__ float s_rfin[OBJ][SPB];

    const int tid = threadIdx.x;
    const int g = tid & 15;    // lane within sample group
    const int p = tid >> 4;    // sample slot in block

    // ---- in-block table prep: lanes 0..7, one table each ----
    if (tid < 8) {
        float w[NT]; float sum = 0.f;
        #pragma unroll
        for (int k = 0; k < NT; ++k) { w[k] = fabsf(ws[tid * NT + k]); sum += w[k]; }
        float rs = 1.f / sum;
        float c = 0.f;
        #pragma unroll
        for (int k = 0; k < NT; ++k) {
            float v = w[k] * rs;
            s_tab[tid * NT + k] = v;
            c += v;
            s_tab[136 + tid * NT + k] = c;
        }
    }

    int s = blockIdx.x * SPB + p;
    const bool active = (s < n);
    if (!active) s = n - 1;

    // ---- my ≤3 candidate elements (e = g + 16k) ----
    const float* arow = attn + (size_t)s * M;
    float mv[3]; unsigned long long myk[3];
    #pragma unroll
    for (int k = 0; k < 3; ++k) {
        int e = g + 16 * k;
        bool ok = e < M;
        float v = ok ? arow[e] : 0.f;
        mv[k] = v;
        myk[k] = ok ? mkkey(v, e) : 0ull;
    }
    // ---- streaming rank (strict >, jax tie-break via index bits) ----
    int rnk0 = 0, rnk1 = 0, rnk2 = 0;
    #pragma unroll
    for (int c4 = 0; c4 < 9; ++c4) {
        float4 t4 = ((const float4*)arow)[c4];
        float vv[4] = {t4.x, t4.y, t4.z, t4.w};
        #pragma unroll
        for (int q = 0; q < 4; ++q) {
            unsigned long long kk = mkkey(vv[q], 4 * c4 + q);
            rnk0 += (kk > myk[0]) ? 1 : 0;
            rnk1 += (kk > myk[1]) ? 1 : 0;
            rnk2 += (kk > myk[2]) ? 1 : 0;
        }
    }
    int rnk[3] = {rnk0, rnk1, rnk2};

    __syncthreads();   // tables ready

    // ---- scatter selected (rank<10 -> unique slot) ----
    const float* brow = boxes + (size_t)s * (4 * M);
    float mA = 0.f;
    #pragma unroll
    for (int k = 0; k < 3; ++k) {
        int e = g + 16 * k;
        if (e < M && rnk[k] < OBJ) {
            float a = 1.f / (1.f + __expf(-mv[k]));
            int r = rnk[k];
            s_att[r][p] = a;
            mA += fabsf(plin_tab(s_tab, 5, a) - 0.5f);
            float x0 = brow[e], y0 = brow[M + e], x1 = brow[2 * M + e], y1 = brow[3 * M + e];
            s_box[0][r][p] = x0; s_box[1][r][p] = y0;
            s_box[2][r][p] = x1; s_box[3][r][p] = y1;
            s_box[4][r][p] = fmaxf(x1 - x0, 0.f) * fmaxf(y1 - y0, 0.f);
        }
    }
    __syncthreads();

    // ---- pass A: 4 of 55 (i<=j) pairs ----
    float mD = 0.f;
    float sc_loc[4];
    #pragma unroll
    for (int t = 0; t < 4; ++t) {
        int q = g + 16 * t;
        bool act = (q < 55);
        int pk = c_p55[act ? q : 0];
        int i = pk >> 4, j = pk & 15;
        float wx = fminf(s_box[2][i][p], s_box[2][j][p]) - fmaxf(s_box[0][i][p], s_box[0][j][p]);
        float wy = fminf(s_box[3][i][p], s_box[3][j][p]) - fmaxf(s_box[1][i][p], s_box[1][j][p]);
        float inter = fmaxf(wx, 0.f) * fmaxf(wy, 0.f);
        float un = s_box[4][i][p] + s_box[4][j][p] - inter + 1e-12f;
        float d = 1.f - inter * __builtin_amdgcn_rcpf(un);
        float relev = s_att[i][p] * s_att[j][p];
        float dd = plin_tab(s_tab, 3, relev) * plin_tab(s_tab, 4, d);
        sc_loc[t] = plin_tab(s_tab, 0, relev) * plin_tab(s_tab, 1, d);
        float dc = fabsf(plin_tab(s_tab, 6, d) - 0.5f);
        if (act) {
            s_dedup[i * OBJ + j][p] = dd;
            s_dedup[j * OBJ + i][p] = dd;
            mD += (i != j) ? 2.f * dc : dc;
        }
    }
    __syncthreads();

    // ---- pass B: 3 of 45 (i<j) pairs; row partials in registers ----
    float racc[OBJ];
    #pragma unroll
    for (int r = 0; r < OBJ; ++r) racc[r] = 0.f;
    #pragma unroll
    for (int t = 0; t < 3; ++t) {
        int q = g + 16 * t;
        bool act = (q < 45);
        int pk = c_p45[act ? q : 0];
        int i = pk >> 4, j = pk & 15;
        float prod = plin_tab(s_tab, 2, 1.f - fabsf(s_att[i][p] - s_att[j][p]));
        #pragma unroll
        for (int a = 0; a < OBJ; ++a) {
            float da = fabsf(s_dedup[a * OBJ + i][p] - s_dedup[a * OBJ + j][p]);
            prod *= plin_tab(s_tab, 2, 1.f - da);
        }
        if (!act) prod = 0.f;
        #pragma unroll
        for (int r = 0; r < OBJ; ++r)
            racc[r] += ((r == i) || (r == j)) ? prod : 0.f;
    }
    // reduce rows across the 16 group lanes (xor masks stay in-group)
    #pragma unroll
    for (int r = 0; r < OBJ; ++r) {
        float v = racc[r];
        v += __shfl_xor(v, 1); v += __shfl_xor(v, 2);
        v += __shfl_xor(v, 4); v += __shfl_xor(v, 8);
        racc[r] = v;
    }
    {
        float c16 = s_tab[136 + 2 * NT + N_PL];
        float c2 = c16 * c16, c4 = c2 * c2, c8 = c4 * c4;
        float diag = c8 * c2 * c16;   // cs2[16]^11
        float myrow = racc[0];
        #pragma unroll
        for (int r = 1; r < OBJ; ++r) myrow = (g == r) ? racc[r] : myrow;
        if (g < OBJ) s_rfin[g][p] = 1.f / (myrow + diag);
    }
    __syncthreads();

    // ---- pass C ----
    float tot = 0.f;
    #pragma unroll
    for (int t = 0; t < 4; ++t) {
        int q = g + 16 * t;
        bool act = (q < 55);
        int pk = c_p55[act ? q : 0];
        int i = pk >> 4, j = pk & 15;
        float term = sc_loc[t] * s_rfin[i][p] * s_rfin[j][p];
        if (act) tot += (i != j) ? 2.f * term : term;
    }
    if (g < OBJ) {
        float ai = s_att[g][p];
        tot += plin_tab(s_tab, 0, ai * ai) * s_rfin[g][p];
    }
    float carg = mA * 0.1f + mD * 0.01f;
    tot  += __shfl_xor(tot, 1);  tot  += __shfl_xor(tot, 2);
    tot  += __shfl_xor(tot, 4);  tot  += __shfl_xor(tot, 8);
    carg += __shfl_xor(carg, 1); carg += __shfl_xor(carg, 2);
    carg += __shfl_xor(carg, 4); carg += __shfl_xor(carg, 8);

    float total = sqrtf(tot + 1e-20f);
    float conf = plin_tab(s_tab, 7, carg);
    float scl = fminf(fmaxf(total, 0.f), 10.f);
    int i0 = (int)scl;
    float f = scl - (float)i0;
    int lo = i0 < OBJ ? i0 : OBJ;
    int hi = (i0 + 1) < OBJ ? (i0 + 1) : OBJ;

    if (active && g <= OBJ) {
        float vv = ((g == lo) ? (1.f - f) : 0.f) + ((g == hi) ? f : 0.f);
        out[(size_t)s * (OBJ + 1) + g] = vv * conf;
    }
}

extern "C" void kernel_launch(void* const* d_in, const int* in_sizes, int n_in,
                              void* d_out, int out_size, void* d_ws, size_t ws_size,
                              hipStream_t stream) {
    const float* boxes = (const float*)d_in[0];
    const float* attn  = (const float*)d_in[1];
    const float* ws    = (const float*)d_in[2];
    float* out = (float*)d_out;
    int n = in_sizes[1] / M;
    int blocks = (n + SPB - 1) / SPB;
    hipLaunchKernelGGL(counter_kernel, dim3(blocks), dim3(BLK), 0, stream,
                       boxes, attn, ws, out, n);
}

// Round 4
// 87.112 us; speedup vs baseline: 1.4111x; 1.4111x over previous
//
#include <hip/hip_runtime.h>
#include <math.h>

#define N_PL 16
#define NT   17      // N_PL+1
#define OBJ  10
#define M    36
#define SPB  4       // samples per block
#define BLK  64      // one wave per block; 16 lanes per sample

// per-sample LDS region layout (stride 273 floats; 273 mod 32 = 17, odd -> bank rotation)
#define R_ATT  0     // 10
#define R_X0   10
#define R_Y0   20
#define R_X1   30
#define R_Y1   40
#define R_AR   50
#define R_DED  60    // 100
#define R_SIM  160   // 100 (full matrix, diagonal unused)
#define R_RF   260   // 10
#define RSTRIDE 273

// packed (i<<4)|j pair tables
__constant__ unsigned char c_p55[55] = {
 0x00,0x01,0x02,0x03,0x04,0x05,0x06,0x07,0x08,0x09,
 0x11,0x12,0x13,0x14,0x15,0x16,0x17,0x18,0x19,
 0x22,0x23,0x24,0x25,0x26,0x27,0x28,0x29,
 0x33,0x34,0x35,0x36,0x37,0x38,0x39,
 0x44,0x45,0x46,0x47,0x48,0x49,
 0x55,0x56,0x57,0x58,0x59,
 0x66,0x67,0x68,0x69,
 0x77,0x78,0x79,
 0x88,0x89,
 0x99};
__constant__ unsigned char c_p45[45] = {
 0x01,0x02,0x03,0x04,0x05,0x06,0x07,0x08,0x09,
 0x12,0x13,0x14,0x15,0x16,0x17,0x18,0x19,
 0x23,0x24,0x25,0x26,0x27,0x28,0x29,
 0x34,0x35,0x36,0x37,0x38,0x39,
 0x45,0x46,0x47,0x48,0x49,
 0x56,0x57,0x58,0x59,
 0x67,0x68,0x69,
 0x78,0x79,
 0x89};

// plin: s_tab[0..135] = wn[8][17], s_tab[136..271] = cs[8][17]
__device__ __forceinline__ float plin_tab(const float* s_tab, int t, float x) {
    const float* wn = s_tab + t * NT;
    const float* cs = s_tab + 136 + t * NT;
    float y = 16.0f * x;
    int idx = (int)y;
    float f = y - (float)idx;
    int i0 = idx < N_PL ? idx : N_PL;
    int i1 = (idx + 1) < N_PL ? (idx + 1) : N_PL;
    return __builtin_fmaf(f, wn[i1], cs[i0]);
}

__device__ __forceinline__ unsigned long long mkkey(float v, int m) {
    unsigned int b = __float_as_uint(v);
    unsigned int u = b ^ (0x80000000u | (unsigned int)((int)b >> 31));
    return ((unsigned long long)u << 6) | (unsigned int)(63 - m);
}

__global__ __launch_bounds__(BLK, 4) void counter_kernel(
    const float* __restrict__ boxes,   // [n,4,36]
    const float* __restrict__ attn,    // [n,36]
    const float* __restrict__ ws,      // [8,17]
    float* __restrict__ out,           // [n,11]
    int n)
{
    __shared__ float s_tab[272];
    __shared__ float s_reg[SPB * RSTRIDE];

    const int tid = threadIdx.x;
    const int g = tid & 15;    // lane within sample group
    const int p = tid >> 4;    // sample slot in block
    float* R = s_reg + p * RSTRIDE;

    // ---- in-block table prep: lanes 0..7, one table each ----
    if (tid < 8) {
        float w[NT]; float sum = 0.f;
        #pragma unroll
        for (int k = 0; k < NT; ++k) { w[k] = fabsf(ws[tid * NT + k]); sum += w[k]; }
        float rs = 1.f / sum;
        float c = 0.f;
        #pragma unroll
        for (int k = 0; k < NT; ++k) {
            float v = w[k] * rs;
            s_tab[tid * NT + k] = v;
            c += v;
            s_tab[136 + tid * NT + k] = c;
        }
    }

    int s = blockIdx.x * SPB + p;
    const bool active = (s < n);
    if (!active) s = n - 1;

    // ---- my <=3 candidate elements (e = g + 16k); streaming rank (no big arrays) ----
    const float* arow = attn + (size_t)s * M;
    float mv[3]; unsigned long long myk[3];
    #pragma unroll
    for (int k = 0; k < 3; ++k) {
        int e = g + 16 * k;
        bool ok = e < M;
        float v = ok ? arow[e] : 0.f;
        mv[k] = v;
        myk[k] = ok ? mkkey(v, e) : 0ull;
    }
    int rnk0 = 0, rnk1 = 0, rnk2 = 0;
    #pragma unroll
    for (int c4 = 0; c4 < 9; ++c4) {
        float4 t4 = ((const float4*)arow)[c4];
        float vv[4] = {t4.x, t4.y, t4.z, t4.w};
        #pragma unroll
        for (int q = 0; q < 4; ++q) {
            unsigned long long kk = mkkey(vv[q], 4 * c4 + q);
            rnk0 += (kk > myk[0]) ? 1 : 0;
            rnk1 += (kk > myk[1]) ? 1 : 0;
            rnk2 += (kk > myk[2]) ? 1 : 0;
        }
    }
    int rnk[3] = {rnk0, rnk1, rnk2};

    __syncthreads();   // tables ready

    // ---- scatter selected (rank<10 -> unique slot = rank) ----
    const float* brow = boxes + (size_t)s * (4 * M);
    float mA = 0.f;
    #pragma unroll
    for (int k = 0; k < 3; ++k) {
        int e = g + 16 * k;
        if (e < M && rnk[k] < OBJ) {
            float a = 1.f / (1.f + __expf(-mv[k]));
            int r = rnk[k];
            R[R_ATT + r] = a;
            mA += fabsf(plin_tab(s_tab, 5, a) - 0.5f);
            float x0 = brow[e], y0 = brow[M + e], x1 = brow[2 * M + e], y1 = brow[3 * M + e];
            R[R_X0 + r] = x0; R[R_Y0 + r] = y0;
            R[R_X1 + r] = x1; R[R_Y1 + r] = y1;
            R[R_AR + r] = fmaxf(x1 - x0, 0.f) * fmaxf(y1 - y0, 0.f);
        }
    }
    __syncthreads();

    // ---- pass A: 4 of 55 (i<=j) pairs: dist, dedup, score(regs), dist_conf ----
    float mD = 0.f;
    float sc_loc[4];
    #pragma unroll
    for (int t = 0; t < 4; ++t) {
        int q = g + 16 * t;
        bool act = (q < 55);
        int pk = c_p55[act ? q : 0];
        int i = pk >> 4, j = pk & 15;
        float wx = fminf(R[R_X1 + i], R[R_X1 + j]) - fmaxf(R[R_X0 + i], R[R_X0 + j]);
        float wy = fminf(R[R_Y1 + i], R[R_Y1 + j]) - fmaxf(R[R_Y0 + i], R[R_Y0 + j]);
        float inter = fmaxf(wx, 0.f) * fmaxf(wy, 0.f);
        float un = R[R_AR + i] + R[R_AR + j] - inter + 1e-12f;
        float d = 1.f - inter * __builtin_amdgcn_rcpf(un);
        float relev = R[R_ATT + i] * R[R_ATT + j];
        float dd = plin_tab(s_tab, 3, relev) * plin_tab(s_tab, 4, d);
        sc_loc[t] = plin_tab(s_tab, 0, relev) * plin_tab(s_tab, 1, d);
        float dc = fabsf(plin_tab(s_tab, 6, d) - 0.5f);
        if (act) {
            R[R_DED + i * OBJ + j] = dd;
            R[R_DED + j * OBJ + i] = dd;
            mD += (i != j) ? 2.f * dc : dc;
        }
    }
    __syncthreads();

    // ---- pass B: 3 of 45 (i<j) pairs -> sim matrix (both triangles) ----
    #pragma unroll
    for (int t = 0; t < 3; ++t) {
        int q = g + 16 * t;
        bool act = (q < 45);
        int pk = c_p45[act ? q : 0];
        int i = pk >> 4, j = pk & 15;
        float prod = plin_tab(s_tab, 2, 1.f - fabsf(R[R_ATT + i] - R[R_ATT + j]));
        #pragma unroll
        for (int a = 0; a < OBJ; ++a) {
            float da = fabsf(R[R_DED + a * OBJ + i] - R[R_DED + a * OBJ + j]);
            prod *= plin_tab(s_tab, 2, 1.f - da);
        }
        if (act) {
            R[R_SIM + i * OBJ + j] = prod;
            R[R_SIM + j * OBJ + i] = prod;
        }
    }
    __syncthreads();

    // ---- row_sims: lane g (g<10) sums its row; diagonal = cs2[16]^11 closed form ----
    if (g < OBJ) {
        float c16 = s_tab[136 + 2 * NT + N_PL];
        float c2 = c16 * c16, c4 = c2 * c2, c8 = c4 * c4;
        float sum = c8 * c2 * c16;   // ^11
        #pragma unroll
        for (int j = 0; j < OBJ; ++j)
            sum += (j == g) ? 0.f : R[R_SIM + g * OBJ + j];
        R[R_RF + g] = 1.f / sum;
    }
    __syncthreads();

    // ---- pass C: total = sum sc*rinv_i*rinv_j (2x off-diag) + correction ----
    float tot = 0.f;
    #pragma unroll
    for (int t = 0; t < 4; ++t) {
        int q = g + 16 * t;
        bool act = (q < 55);
        int pk = c_p55[act ? q : 0];
        int i = pk >> 4, j = pk & 15;
        float term = sc_loc[t] * R[R_RF + i] * R[R_RF + j];
        if (act) tot += (i != j) ? 2.f * term : term;
    }
    if (g < OBJ) {
        float ai = R[R_ATT + g];
        tot += plin_tab(s_tab, 0, ai * ai) * R[R_RF + g];
    }
    float carg = mA * 0.1f + mD * 0.01f;
    tot  += __shfl_xor(tot, 1);  tot  += __shfl_xor(tot, 2);
    tot  += __shfl_xor(tot, 4);  tot  += __shfl_xor(tot, 8);
    carg += __shfl_xor(carg, 1); carg += __shfl_xor(carg, 2);
    carg += __shfl_xor(carg, 4); carg += __shfl_xor(carg, 8);

    float total = sqrtf(tot + 1e-20f);
    float conf = plin_tab(s_tab, 7, carg);
    float scl = fminf(fmaxf(total, 0.f), 10.f);
    int i0 = (int)scl;
    float f = scl - (float)i0;
    int lo = i0 < OBJ ? i0 : OBJ;
    int hi = (i0 + 1) < OBJ ? (i0 + 1) : OBJ;

    if (active && g <= OBJ) {
        float vv = ((g == lo) ? (1.f - f) : 0.f) + ((g == hi) ? f : 0.f);
        out[(size_t)s * (OBJ + 1) + g] = vv * conf;
    }
}

extern "C" void kernel_launch(void* const* d_in, const int* in_sizes, int n_in,
                              void* d_out, int out_size, void* d_ws, size_t ws_size,
                              hipStream_t stream) {
    const float* boxes = (const float*)d_in[0];
    const float* attn  = (const float*)d_in[1];
    const float* ws    = (const float*)d_in[2];
    float* out = (float*)d_out;
    int n = in_sizes[1] / M;
    int blocks = (n + SPB - 1) / SPB;
    hipLaunchKernelGGL(counter_kernel, dim3(blocks), dim3(BLK), 0, stream,
                       boxes, attn, ws, out, n);
}

// Round 5
// 83.382 us; speedup vs baseline: 1.4742x; 1.0447x over previous
//
#include <hip/hip_runtime.h>
#include <math.h>

#define N_PL 16
#define NT   17      // N_PL+1
#define OBJ  10
#define M    36
#define SPB  4       // samples per block
#define BLK  64      // one wave per block; 16 lanes per sample
#define CSTR 12      // dedup/sim row stride (48 B -> b128-aligned rows)

// packed (i<<4)|j pair tables
__constant__ unsigned char c_p55[55] = {
 0x00,0x01,0x02,0x03,0x04,0x05,0x06,0x07,0x08,0x09,
 0x11,0x12,0x13,0x14,0x15,0x16,0x17,0x18,0x19,
 0x22,0x23,0x24,0x25,0x26,0x27,0x28,0x29,
 0x33,0x34,0x35,0x36,0x37,0x38,0x39,
 0x44,0x45,0x46,0x47,0x48,0x49,
 0x55,0x56,0x57,0x58,0x59,
 0x66,0x67,0x68,0x69,
 0x77,0x78,0x79,
 0x88,0x89,
 0x99};
__constant__ unsigned char c_p45[45] = {
 0x01,0x02,0x03,0x04,0x05,0x06,0x07,0x08,0x09,
 0x12,0x13,0x14,0x15,0x16,0x17,0x18,0x19,
 0x23,0x24,0x25,0x26,0x27,0x28,0x29,
 0x34,0x35,0x36,0x37,0x38,0x39,
 0x45,0x46,0x47,0x48,0x49,
 0x56,0x57,0x58,0x59,
 0x67,0x68,0x69,
 0x78,0x79,
 0x89};

// fused plin: tb[k] = (cs[k], wn[min(k+1,16)]) -> one ds_read_b64 per eval
__device__ __forceinline__ float plin2(const float2* tb, float x) {
    float y = 16.0f * x;
    int idx = (int)y;
    float f = y - (float)idx;
    int i0 = idx < N_PL ? idx : N_PL;
    float2 cw = tb[i0];
    return __builtin_fmaf(f, cw.y, cw.x);
}

__device__ __forceinline__ unsigned long long mkkey(float v, int m) {
    unsigned int b = __float_as_uint(v);
    unsigned int u = b ^ (0x80000000u | (unsigned int)((int)b >> 31));
    return ((unsigned long long)u << 6) | (unsigned int)(63 - m);
}

__global__ __launch_bounds__(BLK, 4) void counter_kernel(
    const float* __restrict__ boxes,   // [n,4,36]
    const float* __restrict__ attn,    // [n,36]
    const float* __restrict__ ws,      // [8,17]
    float* __restrict__ out,           // [n,11]
    int n)
{
    __shared__ float2 s_tab2[8 * NT];          // fused (cs, wn+1) tables
    __shared__ float4 s_bx[SPB][OBJ];          // x0,y0,x1,y1
    __shared__ float2 s_aa[SPB][OBJ];          // (att, area)
    __shared__ float  s_ded[SPB][CSTR * OBJ];  // symmetric, stride-12 rows
    __shared__ float  s_sim[SPB][CSTR * OBJ];  // stride-12 rows, diag zeroed
    __shared__ float  s_rf[SPB][OBJ];          // 1/row_sims

    const int tid = threadIdx.x;
    const int g = tid & 15;
    const int p = tid >> 4;

    // ---- in-block table prep: lanes 0..7 ----
    if (tid < 8) {
        float w[NT]; float sum = 0.f;
        #pragma unroll
        for (int k = 0; k < NT; ++k) { w[k] = fabsf(ws[tid * NT + k]); sum += w[k]; }
        float rs = 1.f / sum;
        float wn[NT];
        #pragma unroll
        for (int k = 0; k < NT; ++k) wn[k] = w[k] * rs;
        float c = 0.f;
        #pragma unroll
        for (int k = 0; k < NT; ++k) {
            c += wn[k];
            s_tab2[tid * NT + k] = make_float2(c, wn[k < N_PL ? k + 1 : N_PL]);
        }
    }

    int s = blockIdx.x * SPB + p;
    const bool active = (s < n);
    if (!active) s = n - 1;

    // ---- streaming top-k rank for my <=3 elements ----
    const float* arow = attn + (size_t)s * M;
    float mv[3]; unsigned long long myk[3];
    #pragma unroll
    for (int k = 0; k < 3; ++k) {
        int e = g + 16 * k;
        bool ok = e < M;
        float v = ok ? arow[e] : 0.f;
        mv[k] = v;
        myk[k] = ok ? mkkey(v, e) : 0ull;
    }
    int rnk0 = 0, rnk1 = 0, rnk2 = 0;
    #pragma unroll
    for (int c4 = 0; c4 < 9; ++c4) {
        float4 t4 = ((const float4*)arow)[c4];
        float vv[4] = {t4.x, t4.y, t4.z, t4.w};
        #pragma unroll
        for (int q = 0; q < 4; ++q) {
            unsigned long long kk = mkkey(vv[q], 4 * c4 + q);
            rnk0 += (kk > myk[0]) ? 1 : 0;
            rnk1 += (kk > myk[1]) ? 1 : 0;
            rnk2 += (kk > myk[2]) ? 1 : 0;
        }
    }
    int rnk[3] = {rnk0, rnk1, rnk2};

    __syncthreads();   // tables ready

    // ---- scatter selected (rank<10 -> unique slot) ----
    const float* brow = boxes + (size_t)s * (4 * M);
    float mA = 0.f;
    #pragma unroll
    for (int k = 0; k < 3; ++k) {
        int e = g + 16 * k;
        if (e < M && rnk[k] < OBJ) {
            float a = 1.f / (1.f + __expf(-mv[k]));
            int r = rnk[k];
            mA += fabsf(plin2(s_tab2 + 5 * NT, a) - 0.5f);
            float x0 = brow[e], y0 = brow[M + e], x1 = brow[2 * M + e], y1 = brow[3 * M + e];
            s_bx[p][r] = make_float4(x0, y0, x1, y1);
            s_aa[p][r] = make_float2(a, fmaxf(x1 - x0, 0.f) * fmaxf(y1 - y0, 0.f));
        }
    }
    __syncthreads();

    // ---- pass A: 4 of 55 (i<=j) pairs ----
    float mD = 0.f;
    float sc_loc[4];
    int pkA[4];
    #pragma unroll
    for (int t = 0; t < 4; ++t) {
        int q = g + 16 * t;
        bool act = (q < 55);
        int pk = c_p55[act ? q : 0];
        pkA[t] = pk;
        int i = pk >> 4, j = pk & 15;
        float4 bi = s_bx[p][i], bj = s_bx[p][j];
        float2 ai = s_aa[p][i], aj = s_aa[p][j];
        float wx = fminf(bi.z, bj.z) - fmaxf(bi.x, bj.x);
        float wy = fminf(bi.w, bj.w) - fmaxf(bi.y, bj.y);
        float inter = fmaxf(wx, 0.f) * fmaxf(wy, 0.f);
        float un = ai.y + aj.y - inter + 1e-12f;
        float d = 1.f - inter * __builtin_amdgcn_rcpf(un);
        float relev = ai.x * aj.x;
        float dd = plin2(s_tab2 + 3 * NT, relev) * plin2(s_tab2 + 4 * NT, d);
        sc_loc[t] = plin2(s_tab2 + 0 * NT, relev) * plin2(s_tab2 + 1 * NT, d);
        float dc = fabsf(plin2(s_tab2 + 6 * NT, d) - 0.5f);
        if (act) {
            s_ded[p][i * CSTR + j] = dd;
            s_ded[p][j * CSTR + i] = dd;
            mD += (i != j) ? 2.f * dc : dc;
        }
    }
    __syncthreads();

    // ---- pass B: 3 of 45 (i<j) pairs -> sim matrix; also zero diag ----
    if (g < OBJ) s_sim[p][g * CSTR + g] = 0.f;
    #pragma unroll
    for (int t = 0; t < 3; ++t) {
        int q = g + 16 * t;
        bool act = (q < 45);
        int pk = c_p45[act ? q : 0];
        int i = pk >> 4, j = pk & 15;
        float2 ai = s_aa[p][i], aj = s_aa[p][j];
        float prod = plin2(s_tab2 + 2 * NT, 1.f - fabsf(ai.x - aj.x));
        const float* ci = &s_ded[p][i * CSTR];
        const float* cj = &s_ded[p][j * CSTR];
        float4 ci0 = *(const float4*)ci;
        float4 ci1 = *(const float4*)(ci + 4);
        float2 ci2 = *(const float2*)(ci + 8);
        float4 cj0 = *(const float4*)cj;
        float4 cj1 = *(const float4*)(cj + 4);
        float2 cj2 = *(const float2*)(cj + 8);
        const float2* tb2 = s_tab2 + 2 * NT;
        prod *= plin2(tb2, 1.f - fabsf(ci0.x - cj0.x));
        prod *= plin2(tb2, 1.f - fabsf(ci0.y - cj0.y));
        prod *= plin2(tb2, 1.f - fabsf(ci0.z - cj0.z));
        prod *= plin2(tb2, 1.f - fabsf(ci0.w - cj0.w));
        prod *= plin2(tb2, 1.f - fabsf(ci1.x - cj1.x));
        prod *= plin2(tb2, 1.f - fabsf(ci1.y - cj1.y));
        prod *= plin2(tb2, 1.f - fabsf(ci1.z - cj1.z));
        prod *= plin2(tb2, 1.f - fabsf(ci1.w - cj1.w));
        prod *= plin2(tb2, 1.f - fabsf(ci2.x - cj2.x));
        prod *= plin2(tb2, 1.f - fabsf(ci2.y - cj2.y));
        if (act) {
            s_sim[p][i * CSTR + j] = prod;
            s_sim[p][j * CSTR + i] = prod;
        }
    }
    __syncthreads();

    // ---- row_sims: lane g sums its row (diag slot zeroed; add closed form) ----
    if (g < OBJ) {
        float c16 = s_tab2[2 * NT + N_PL].x;
        float c2 = c16 * c16, c4 = c2 * c2, c8 = c4 * c4;
        float diag = c8 * c2 * c16;   // cs2[16]^11
        const float* rw = &s_sim[p][g * CSTR];
        float4 r0 = *(const float4*)rw;
        float4 r1 = *(const float4*)(rw + 4);
        float2 r2 = *(const float2*)(rw + 8);
        float sum = diag + r0.x + r0.y + r0.z + r0.w
                         + r1.x + r1.y + r1.z + r1.w + r2.x + r2.y;
        s_rf[p][g] = 1.f / sum;
    }
    __syncthreads();

    // ---- pass C ----
    float tot = 0.f;
    #pragma unroll
    for (int t = 0; t < 4; ++t) {
        int q = g + 16 * t;
        bool act = (q < 55);
        int pk = pkA[t];
        int i = pk >> 4, j = pk & 15;
        float term = sc_loc[t] * s_rf[p][i] * s_rf[p][j];
        if (act) tot += (i != j) ? 2.f * term : term;
    }
    if (g < OBJ) {
        float ai = s_aa[p][g].x;
        tot += plin2(s_tab2 + 0 * NT, ai * ai) * s_rf[p][g];
    }
    float carg = mA * 0.1f + mD * 0.01f;
    tot  += __shfl_xor(tot, 1);  tot  += __shfl_xor(tot, 2);
    tot  += __shfl_xor(tot, 4);  tot  += __shfl_xor(tot, 8);
    carg += __shfl_xor(carg, 1); carg += __shfl_xor(carg, 2);
    carg += __shfl_xor(carg, 4); carg += __shfl_xor(carg, 8);

    float total = sqrtf(tot + 1e-20f);
    float conf = plin2(s_tab2 + 7 * NT, carg);
    float scl = fminf(fmaxf(total, 0.f), 10.f);
    int i0 = (int)scl;
    float f = scl - (float)i0;
    int lo = i0 < OBJ ? i0 : OBJ;
    int hi = (i0 + 1) < OBJ ? (i0 + 1) : OBJ;

    if (active && g <= OBJ) {
        float vv = ((g == lo) ? (1.f - f) : 0.f) + ((g == hi) ? f : 0.f);
        out[(size_t)s * (OBJ + 1) + g] = vv * conf;
    }
}

extern "C" void kernel_launch(void* const* d_in, const int* in_sizes, int n_in,
                              void* d_out, int out_size, void* d_ws, size_t ws_size,
                              hipStream_t stream) {
    const float* boxes = (const float*)d_in[0];
    const float* attn  = (const float*)d_in[1];
    const float* ws    = (const float*)d_in[2];
    float* out = (float*)d_out;
    int n = in_sizes[1] / M;
    int blocks = (n + SPB - 1) / SPB;
    hipLaunchKernelGGL(counter_kernel, dim3(blocks), dim3(BLK), 0, stream,
                       boxes, attn, ws, out, n);
}